// Round 12
// baseline (123.717 us; speedup 1.0000x reference)
//
#include <hip/hip_runtime.h>

#define HW 128      // H == W
#define CC 64       // C
#define C8V 8       // C/8
#define NB 16       // B
#define LOG2E 1.44269504088896f

typedef _Float16 h1;
typedef _Float16 h2 __attribute__((ext_vector_type(2)));
typedef _Float16 half8 __attribute__((ext_vector_type(8)));
typedef float float16v __attribute__((ext_vector_type(16)));
typedef uint uv4 __attribute__((ext_vector_type(4)));
typedef float fv4 __attribute__((ext_vector_type(4)));
typedef uint uv2 __attribute__((ext_vector_type(2)));

__device__ __forceinline__ uint packh2(float a, float b) {
#if __has_builtin(__builtin_amdgcn_cvt_pkrtz)
  return __builtin_bit_cast(uint, __builtin_amdgcn_cvt_pkrtz(a, b));
#else
  h2 v; v[0] = (h1)a; v[1] = (h1)b; return __builtin_bit_cast(uint, v);
#endif
}
__device__ __forceinline__ ushort f2h(float a) { h1 v = (h1)a; return __builtin_bit_cast(ushort, v); }
__device__ __forceinline__ float  h2f(ushort a) { return (float)__builtin_bit_cast(h1, a); }

__device__ __forceinline__ float fexp2(float x) {
#if __has_builtin(__builtin_amdgcn_exp2f)
  return __builtin_amdgcn_exp2f(x);
#else
  return exp2f(x);
#endif
}

template <typename T>
__device__ __forceinline__ T ntload(const T* p) {
#if __has_builtin(__builtin_nontemporal_load)
  return __builtin_nontemporal_load(p);
#else
  return *p;
#endif
}
template <typename T>
__device__ __forceinline__ void ntstore(T* p, T v) {
#if __has_builtin(__builtin_nontemporal_store)
  __builtin_nontemporal_store(v, p);
#else
  *p = v;
#endif
}

__device__ __forceinline__ float16v mfma16(uv4 a, uv4 b, float16v c) {
  return __builtin_amdgcn_mfma_f32_32x32x16_f16(
      __builtin_bit_cast(half8, a), __builtin_bit_cast(half8, b), c, 0, 0, 0);
}

// ---------------------------------------------------------------------------
// K0: one-time weight prep. W_frag[(ks*2+hi)*96 + o][e] = W[o][8*hi+16*ks+e]
// (f16, q-rows pre-scaled by log2e). bias_f[96] f32 (bq scaled).
// ---------------------------------------------------------------------------
__global__ __launch_bounds__(256) void k_prep(
    const float* __restrict__ Wq, const float* __restrict__ bq,
    const float* __restrict__ Wk, const float* __restrict__ bk,
    const float* __restrict__ Wv, const float* __restrict__ bv,
    ushort* __restrict__ W_frag, float* __restrict__ bias_f)
{
  int idx = blockIdx.x * 256 + threadIdx.x;   // 24 blocks -> 6144
  if (idx < 6144) {
    int g = idx >> 3, e = idx & 7;
    int kshi = g / 96, o = g % 96;
    int ks = kshi >> 1, hi = kshi & 1;
    int c = 8 * hi + 16 * ks + e;
    float val = (o < 8)  ? Wq[o * 64 + c] * LOG2E
              : (o < 16) ? Wk[(o - 8) * 64 + c]
              : (o < 80) ? Wv[(o - 16) * 64 + c] : 0.f;
    W_frag[idx] = f2h(val);
  }
  if (blockIdx.x == 0 && threadIdx.x < 96) {
    int t = threadIdx.x;
    bias_f[t] = (t < 8) ? bq[t] * LOG2E : (t < 16) ? bk[t - 8] : (t < 80) ? bv[t - 16] : 0.f;
  }
}

// ---------------------------------------------------------------------------
// K1: projection GEMM. One block per (b, h) row, 4 waves. A-fragments from
// W_frag (global, L1-hot); B-fragments packed from plane-strided x loads.
// Emits q,k 8-ch pixel-major [b][h][w][8] + transposed copies; v planes.
// ---------------------------------------------------------------------------
__global__ __launch_bounds__(256) void k_proj(
    const float* __restrict__ x, const ushort* __restrict__ W_frag,
    const float* __restrict__ bias_f,
    ushort* __restrict__ q, ushort* __restrict__ k,
    ushort* __restrict__ qT, ushort* __restrict__ kT,
    ushort* __restrict__ v)
{
  alignas(16) __shared__ ushort smem[10496];  // o_l[64][128] | qk_l[128][18]
  __shared__ float bias_l[96];
  ushort* o_l  = smem;            // v channels [ch][w]
  ushort* qk_l = smem + 8192;     // [w][18]

  int t = threadIdx.x;
  int lane = t & 63, wv = t >> 6, hi = lane >> 5;
  int b = blockIdx.x >> 7, r = blockIdx.x & 127;
  if (t < 96) bias_l[t] = bias_f[t];

  int w = 32 * wv + (lane & 31);
  const float* xw = x + (size_t)(b * CC) * (HW * HW) + (size_t)r * HW + w;
  const size_t PL = (size_t)HW * HW;

  float16v acc0 = {}, acc1 = {}, acc2 = {};
  #pragma unroll
  for (int ks = 0; ks < 4; ++ks) {
    int c0 = 8 * hi + 16 * ks;
    uint bx[4];
    #pragma unroll
    for (int e2 = 0; e2 < 4; ++e2) {
      float f0 = xw[(size_t)(c0 + 2 * e2) * PL];
      float f1 = xw[(size_t)(c0 + 2 * e2 + 1) * PL];
      bx[e2] = packh2(f0, f1);
    }
    uv4 Bx = {bx[0], bx[1], bx[2], bx[3]};
    const ushort* wf = W_frag + (size_t)(ks * 2 + hi) * 96 * 8;
    uv4 a0 = *(const uv4*)(wf + (lane & 31) * 8);
    uv4 a1 = *(const uv4*)(wf + ((lane & 31) + 32) * 8);
    uv4 a2 = *(const uv4*)(wf + ((lane & 31) + 64) * 8);
    acc0 = mfma16(a0, Bx, acc0);
    acc1 = mfma16(a1, Bx, acc1);
    acc2 = mfma16(a2, Bx, acc2);
  }
  __syncthreads();

  #pragma unroll
  for (int reg = 0; reg < 16; ++reg) {
    int orow = (reg & 3) + 8 * (reg >> 2) + 4 * hi;   // 0..31
    float v0 = acc0[reg] + bias_l[orow];
    if (orow < 16) qk_l[w * 18 + orow] = f2h(v0);
    else           o_l[(orow - 16) * 128 + w] = f2h(v0);
    o_l[(orow + 16) * 128 + w] = f2h(acc1[reg] + bias_l[orow + 32]);
    if (orow < 16)
      o_l[(orow + 48) * 128 + w] = f2h(acc2[reg] + bias_l[orow + 64]);
  }
  __syncthreads();

  {
    int pix = t & 127, isk = t >> 7;
    const ushort* src = &qk_l[pix * 18 + isk * 8];
    uint d0 = *(const uint*)(src + 0);
    uint d1 = *(const uint*)(src + 2);
    uint d2 = *(const uint*)(src + 4);
    uint d3 = *(const uint*)(src + 6);
    uv4 val = {d0, d1, d2, d3};
    ushort* dstn = (isk ? k : q)  + ((size_t)(b * HW + r) * HW + pix) * 8;
    ushort* dstt = (isk ? kT : qT) + ((size_t)(b * HW + pix) * HW + r) * 8;
    *(uv4*)dstn = val;
    *(uv4*)dstt = val;
  }
  ushort* vb = v + (size_t)(b * CC) * PL + (size_t)r * HW;
  #pragma unroll
  for (int i = 0; i < 4; ++i) {
    int idx = t + 256 * i; int o_ = idx >> 4, w8 = idx & 15;
    *(uv4*)(vb + (size_t)o_ * PL + w8 * 8) = *(const uv4*)&o_l[o_ * 128 + w8 * 8];
  }
}

// ---------------------------------------------------------------------------
// K2: v -> vT plane transposes.
// ---------------------------------------------------------------------------
__global__ __launch_bounds__(256) void k_transpose_v(const ushort* __restrict__ v,
                                                     ushort* __restrict__ vT)
{
  __shared__ ushort tl[128 * 130];
  int t = threadIdx.x;
  size_t base = (size_t)blockIdx.x * (HW * HW);
  const uint* ip = (const uint*)(v + base);
  uint* op = (uint*)(vT + base);
  int c2 = t & 63;
  int r0 = t >> 6;
  for (int it = 0; it < 32; ++it) {
    int r = it * 4 + r0;
    uint val = ip[r * 64 + c2];
    *(uint*)&tl[r * 130 + c2 * 2] = val;
  }
  __syncthreads();
  for (int it = 0; it < 32; ++it) {
    int wcol = it * 4 + r0;
    int hh = c2 * 2;
    uint lo = tl[hh * 130 + wcol];
    uint hi = tl[(hh + 1) * 130 + wcol];
    op[wcol * 64 + c2] = lo | (hi << 16);
  }
}

// ---------------------------------------------------------------------------
// K3: MFMA row attention, BOTH passes. blocks [0,2048) = W-pass (no mask),
// [2048,4096) = H-pass (diag mask). Q/K 8-ch pixel-major, zero half from
// registers. Softmax in exp2 domain. Outputs stored non-temporal.
// ---------------------------------------------------------------------------
__global__ __launch_bounds__(256, 4) void k_attn_both(
    const ushort* __restrict__ qn, const ushort* __restrict__ kn,
    const ushort* __restrict__ qT, const ushort* __restrict__ kT,
    const ushort* __restrict__ vn, const ushort* __restrict__ vT,
    ushort* __restrict__ oW_, float* __restrict__ mW_, float* __restrict__ sW_,
    ushort* __restrict__ oH_, float* __restrict__ mH_, float* __restrict__ sH_)
{
  alignas(16) __shared__ uint V_l[64 * 64];   // 16KB, [c][j] swizzled

  int t = threadIdx.x;
  int lane = t & 63, wv = t >> 6;
  int hi = lane >> 5;
  int bid = blockIdx.x & 2047;
  bool maskf = blockIdx.x >= 2048;
  const ushort* qp = maskf ? qT : qn;
  const ushort* kp = maskf ? kT : kn;
  const ushort* vp = maskf ? vT : vn;
  ushort* op = maskf ? oH_ : oW_;
  float* mo = maskf ? mH_ : mW_;
  float* so = maskf ? sH_ : sW_;

  int b = bid >> 7, r = bid & 127;
  size_t plane32 = (size_t)(HW * HW) / 2;
  size_t pixbase = (size_t)(b * HW + r) * HW * 8;

  int qg = 32 * wv + (lane & 31);
  uv4 Bq = {0, 0, 0, 0};
  uv4 ka[4] = {{0,0,0,0}, {0,0,0,0}, {0,0,0,0}, {0,0,0,0}};
  if (hi == 0) {
    Bq = *(const uv4*)(qp + pixbase + (size_t)qg * 8);
    #pragma unroll
    for (int mt = 0; mt < 4; ++mt)
      ka[mt] = *(const uv4*)(kp + pixbase + (size_t)((lane & 31) + 32 * mt) * 8);
  }

  const uint* vrow = (const uint*)vp + (size_t)(b * CC) * plane32 + (size_t)r * 64;
  #pragma unroll
  for (int i = 0; i < 4; ++i) {
    int idx = t + 256 * i; int c = idx >> 4, j4 = idx & 15;
    uv4 val = *(const uv4*)(vrow + (size_t)c * plane32 + 4 * j4);
    uint byteoff = c * 256 + ((16 * j4) ^ ((c & 15) << 4));
    *(uv4*)((char*)V_l + byteoff) = val;
  }
  __syncthreads();

  float16v e[4];
  #pragma unroll
  for (int mt = 0; mt < 4; ++mt) {
    float16v z = {};
    e[mt] = mfma16(ka[mt], Bq, z);
  }

  if (maskf) {
    #pragma unroll
    for (int mt = 0; mt < 4; ++mt)
      #pragma unroll
      for (int reg = 0; reg < 16; ++reg) {
        int key = 32 * mt + ((reg & 3) + 8 * (reg >> 2) + 4 * hi);
        e[mt][reg] = (key == qg) ? -INFINITY : e[mt][reg];
      }
  }

  float m = -INFINITY;
  #pragma unroll
  for (int mt = 0; mt < 4; ++mt)
    #pragma unroll
    for (int reg = 0; reg < 16; reg += 2)
      m = fmaxf(m, fmaxf(e[mt][reg], e[mt][reg + 1]));
  m = fmaxf(m, __shfl_xor(m, 32));

  float s0 = 0.f, s1 = 0.f, s2 = 0.f, s3 = 0.f;
  #pragma unroll
  for (int mt = 0; mt < 4; ++mt) {
    #pragma unroll
    for (int reg = 0; reg < 16; reg += 4) {
      float p0 = fexp2(e[mt][reg + 0] - m);
      float p1 = fexp2(e[mt][reg + 1] - m);
      float p2 = fexp2(e[mt][reg + 2] - m);
      float p3 = fexp2(e[mt][reg + 3] - m);
      e[mt][reg + 0] = p0; e[mt][reg + 1] = p1;
      e[mt][reg + 2] = p2; e[mt][reg + 3] = p3;
      s0 += p0; s1 += p1; s2 += p2; s3 += p3;
    }
  }
  float s = (s0 + s1) + (s2 + s3);
  s += __shfl_xor(s, 32);
  if (lane < 32) {
    ntstore(&mo[(size_t)bid * HW + qg], m);
    ntstore(&so[(size_t)bid * HW + qg], s);
  }

  float16v acc0 = {}, acc1 = {};
  #pragma unroll
  for (int s8 = 0; s8 < 8; ++s8) {
    int mt = s8 >> 1, hf = s8 & 1;
    float p0 = e[mt][8 * hf + 0], p1 = e[mt][8 * hf + 1];
    float p2 = e[mt][8 * hf + 2], p3 = e[mt][8 * hf + 3];
    float p4 = e[mt][8 * hf + 4], p5 = e[mt][8 * hf + 5];
    float p6 = e[mt][8 * hf + 6], p7 = e[mt][8 * hf + 7];
    uint X = packh2(p0, p1), Y = packh2(p2, p3), Z = packh2(p4, p5), Wp = packh2(p6, p7);
    uint Xs = __shfl_xor(X, 32), Ys = __shfl_xor(Y, 32);
    uint Zs = __shfl_xor(Z, 32), Ws = __shfl_xor(Wp, 32);
    uv4 Bp;
    Bp[0] = (hi == 0) ? X  : Zs;
    Bp[1] = (hi == 0) ? Y  : Ws;
    Bp[2] = (hi == 0) ? Xs : Z;
    Bp[3] = (hi == 0) ? Ys : Wp;
    #pragma unroll
    for (int ct = 0; ct < 2; ++ct) {
      int c = (lane & 31) + 32 * ct;
      uint byteoff = c * 256 + ((16 * (hi + 2 * s8)) ^ ((c & 15) << 4));
      uv4 va = *(const uv4*)((const char*)V_l + byteoff);
      if (ct == 0) acc0 = mfma16(va, Bp, acc0);
      else         acc1 = mfma16(va, Bp, acc1);
    }
  }

  __syncthreads();
  ushort* o_l = (ushort*)V_l;
  int w = 32 * wv + (lane & 31);
  #pragma unroll
  for (int reg = 0; reg < 16; ++reg) {
    int c = (reg & 3) + 8 * (reg >> 2) + 4 * hi;
    o_l[(c +  0) * 128 + w] = f2h(acc0[reg]);
    o_l[(c + 32) * 128 + w] = f2h(acc1[reg]);
  }
  __syncthreads();
  ushort* ob = op + (size_t)(b * CC) * (HW * HW) + (size_t)r * HW;
  #pragma unroll
  for (int i = 0; i < 4; ++i) {
    int idx = t + 256 * i; int c = idx >> 4, w8 = idx & 15;
    ntstore((uv4*)(ob + (size_t)c * (HW * HW) + w8 * 8), *(const uv4*)&o_l[c * 128 + w8 * 8]);
  }
}

// ---------------------------------------------------------------------------
// K4a: per-pixel alphas (f16), exp2 domain. aHT [b][w][h]; aW [b][h][w].
// ---------------------------------------------------------------------------
__global__ __launch_bounds__(256) void k_alpha(
    const float* __restrict__ mH, const float* __restrict__ sH,
    const float* __restrict__ mW, const float* __restrict__ sW,
    ushort* __restrict__ aHT, ushort* __restrict__ aWn)
{
  __shared__ float mw_l[128 * 9], sw_l[128 * 9];   // [h][w]
  __shared__ ushort aw_l[128 * 10];                // [h][w]
  int t = threadIdx.x;
  int b = blockIdx.x >> 4, ws = blockIdx.x & 15;
  int w0 = ws * 8;
  const int PL = HW * HW;

  #pragma unroll
  for (int i = 0; i < 4; ++i) {
    int p = t + 256 * i;
    int w = p & 7, h = p >> 3;
    mw_l[h * 9 + w] = mW[(size_t)b * PL + h * HW + w0 + w];
    sw_l[h * 9 + w] = sW[(size_t)b * PL + h * HW + w0 + w];
  }
  __syncthreads();
  #pragma unroll
  for (int i = 0; i < 4; ++i) {
    int p = t + 256 * i;
    int h = p & 127, w = p >> 7;
    size_t tidx = (size_t)b * PL + (size_t)(w0 + w) * HW + h;
    float mh = mH[tidx], sh = sH[tidx];
    float mw = mw_l[h * 9 + w], sw = sw_l[h * 9 + w];
    float mm = fmaxf(mh, mw);
    float eh = fexp2(mh - mm), ew = fexp2(mw - mm);
    float inv = 1.f / (sh * eh + sw * ew);
    aHT[tidx] = f2h(eh * inv);
    aw_l[h * 10 + w] = f2h(ew * inv);
  }
  __syncthreads();
  #pragma unroll
  for (int i = 0; i < 4; ++i) {
    int p = t + 256 * i;
    int w = p & 7, h = p >> 3;
    aWn[(size_t)b * PL + (size_t)h * HW + w0 + w] = aw_l[h * 10 + w];
  }
}

// ---------------------------------------------------------------------------
// K4b: merge v6. Block = (b, 2-ch group, 32-w stripe). Grid 2048. ONE barrier.
// T14 issue-early: stage loads + alpha_W loads issued before any compute;
// all single-use streams (oHT, oW, x, out) non-temporal; alphas stay cached.
// ---------------------------------------------------------------------------
__global__ __launch_bounds__(256) void k_merge(
    const ushort* __restrict__ oHT, const ushort* __restrict__ oW,
    const ushort* __restrict__ aHT, const ushort* __restrict__ aWn,
    const float* __restrict__ x, const float* __restrict__ gamma,
    float* __restrict__ out)
{
  alignas(16) __shared__ ushort otile[2 * 32 * 132];  // [ch][w][h], h-stride 132
  int t = threadIdx.x;
  int bid = blockIdx.x;
  int wsel = bid & 3, cg = (bid >> 2) & 31, b = bid >> 7;
  int w0 = wsel * 32;
  float g = gamma[0];
  const int PL = HW * HW;

  // A: issue ALL stage loads up front (8 independent vector loads in flight)
  uv4 ov[4], av[4];
  #pragma unroll
  for (int i = 0; i < 4; ++i) {
    int p = t + 256 * i;
    int ch = p >> 9, rest = p & 511;
    int w = rest >> 4, hg = rest & 15;
    size_t cbase = (size_t)(b * CC + cg * 2 + ch) * PL;
    ov[i] = ntload((const uv4*)(oHT + cbase + (size_t)(w0 + w) * HW + hg * 8));
    av[i] = *(const uv4*)(aHT + (size_t)b * PL + (size_t)(w0 + w) * HW + hg * 8);
  }
  // B: issue ch-independent consume loads (alpha_W per pixel)
  uv2 awp[4];
  #pragma unroll
  for (int i = 0; i < 2; ++i) {
    int p = t + 256 * i;
    int w4 = p & 7, hh2 = p >> 3;
    #pragma unroll
    for (int rr = 0; rr < 2; ++rr) {
      int hh = 2 * hh2 + rr;
      awp[i * 2 + rr] = *(const uv2*)(aWn + (size_t)b * PL + (size_t)hh * HW + w0 + 4 * w4);
    }
  }
  // C: stage compute + LDS writes (waits only on ov/av)
  #pragma unroll
  for (int i = 0; i < 4; ++i) {
    int p = t + 256 * i;
    int ch = p >> 9, rest = p & 511;
    int w = rest >> 4, hg = rest & 15;
    uv4 res;
    #pragma unroll
    for (int jj = 0; jj < 4; ++jj) {
      h2 o2 = __builtin_bit_cast(h2, ov[i][jj]);
      h2 a2 = __builtin_bit_cast(h2, av[i][jj]);
      res[jj] = __builtin_bit_cast(uint, o2 * a2);
    }
    *(uv4*)&otile[(ch * 32 + w) * 132 + hg * 8] = res;
  }
  __syncthreads();

  // D: consume — loads at iteration top, math from regs + LDS, nt store
  #pragma unroll
  for (int ch = 0; ch < 2; ++ch) {
    size_t cbase = (size_t)(b * CC + cg * 2 + ch) * PL;
    const ushort* otc = &otile[ch * 32 * 132];
    #pragma unroll
    for (int i = 0; i < 2; ++i) {
      int p = t + 256 * i;
      int w4 = p & 7, hh2 = p >> 3;
      // issue global loads for both rr first (4 independent loads)
      uv2 ow2a[2]; fv4 xva[2];
      #pragma unroll
      for (int rr = 0; rr < 2; ++rr) {
        int hh = 2 * hh2 + rr;
        size_t base = cbase + (size_t)hh * HW + w0 + 4 * w4;
        ow2a[rr] = ntload((const uv2*)(oW + base));
        xva[rr]  = ntload((const fv4*)(x + base));
      }
      float th0[4], th1[4];
      #pragma unroll
      for (int j = 0; j < 4; ++j) {
        uint pk = *(const uint*)&otc[(4 * w4 + j) * 132 + 2 * hh2];
        th0[j] = h2f((ushort)(pk & 0xffff));
        th1[j] = h2f((ushort)(pk >> 16));
      }
      #pragma unroll
      for (int rr = 0; rr < 2; ++rr) {
        int hh = 2 * hh2 + rr;
        const float* th = rr ? th1 : th0;
        size_t base = cbase + (size_t)hh * HW + w0 + 4 * w4;
        uv2 aw2 = awp[i * 2 + rr];
        uv2 ow2 = ow2a[rr];
        fv4 xv = xva[rr];
        fv4 res;
        res[0] = g * (th[0] + h2f((ushort)(ow2[0] & 0xffff)) * h2f((ushort)(aw2[0] & 0xffff))) + xv[0];
        res[1] = g * (th[1] + h2f((ushort)(ow2[0] >> 16))    * h2f((ushort)(aw2[0] >> 16)))    + xv[1];
        res[2] = g * (th[2] + h2f((ushort)(ow2[1] & 0xffff)) * h2f((ushort)(aw2[1] & 0xffff))) + xv[2];
        res[3] = g * (th[3] + h2f((ushort)(ow2[1] >> 16))    * h2f((ushort)(aw2[1] >> 16)))    + xv[3];
        ntstore((fv4*)(out + base), res);
      }
    }
  }
}

extern "C" void kernel_launch(void* const* d_in, const int* in_sizes, int n_in,
                              void* d_out, int out_size, void* d_ws, size_t ws_size,
                              hipStream_t stream)
{
  const float* x     = (const float*)d_in[0];
  const float* Wq    = (const float*)d_in[1];
  const float* bq    = (const float*)d_in[2];
  const float* Wk    = (const float*)d_in[3];
  const float* bk    = (const float*)d_in[4];
  const float* Wv    = (const float*)d_in[5];
  const float* bv    = (const float*)d_in[6];
  const float* gamma = (const float*)d_in[7];
  float* out = (float*)d_out;

  char* w = (char*)d_ws;
  size_t np = (size_t)NB * HW * HW;
  ushort* W_frag = (ushort*)w; w += 6144 * 2;
  float*  bias_f = (float*)w;  w += 96 * 4 + 320;   // keep 16B alignment
  ushort* q   = (ushort*)w;  w += np * 8 * 2;   // pixel-major 8ch
  ushort* k   = (ushort*)w;  w += np * 8 * 2;
  ushort* qT  = (ushort*)w;  w += np * 8 * 2;
  ushort* kT  = (ushort*)w;  w += np * 8 * 2;
  ushort* v   = (ushort*)w;  w += np * CC * 2;
  ushort* vT  = (ushort*)w;  w += np * CC * 2;
  ushort* oW  = (ushort*)w;  w += np * CC * 2;
  ushort* oHT = (ushort*)w;  w += np * CC * 2;
  float* mW = (float*)w;  w += np * 4;
  float* sW = (float*)w;  w += np * 4;
  float* mH = (float*)w;  w += np * 4;
  float* sH = (float*)w;  w += np * 4;
  ushort* aHT = (ushort*)w; w += np * 2;
  ushort* aWn = (ushort*)w; w += np * 2;
  if ((size_t)(w - (char*)d_ws) > ws_size) return;

  k_prep<<<24, 256, 0, stream>>>(Wq, bq, Wk, bk, Wv, bv, W_frag, bias_f);
  k_proj<<<NB * HW, 256, 0, stream>>>(x, W_frag, bias_f, q, k, qT, kT, v);
  k_transpose_v<<<NB * CC, 256, 0, stream>>>(v, vT);
  k_attn_both<<<2 * NB * HW, 256, 0, stream>>>(q, k, qT, kT, v, vT,
                                               oW, mW, sW, oHT, mH, sH);
  k_alpha<<<NB * 16, 256, 0, stream>>>(mH, sH, mW, sW, aHT, aWn);
  k_merge<<<NB * 32 * 4, 256, 0, stream>>>(oHT, oW, aHT, aWn, x, gamma, out);
}

// Round 13
// 107.434 us; speedup vs baseline: 1.1516x; 1.1516x over previous
//
#include <hip/hip_runtime.h>

#define HW 128      // H == W
#define CC 64       // C
#define C8V 8       // C/8
#define NB 16       // B
#define LOG2E 1.44269504088896f

typedef _Float16 h1;
typedef _Float16 h2 __attribute__((ext_vector_type(2)));
typedef _Float16 half8 __attribute__((ext_vector_type(8)));
typedef float float16v __attribute__((ext_vector_type(16)));
typedef uint uv4 __attribute__((ext_vector_type(4)));

__device__ __forceinline__ uint packh2(float a, float b) {
#if __has_builtin(__builtin_amdgcn_cvt_pkrtz)
  return __builtin_bit_cast(uint, __builtin_amdgcn_cvt_pkrtz(a, b));
#else
  h2 v; v[0] = (h1)a; v[1] = (h1)b; return __builtin_bit_cast(uint, v);
#endif
}
__device__ __forceinline__ ushort f2h(float a) { h1 v = (h1)a; return __builtin_bit_cast(ushort, v); }
__device__ __forceinline__ float  h2f(ushort a) { return (float)__builtin_bit_cast(h1, a); }

__device__ __forceinline__ float fexp2(float x) {
#if __has_builtin(__builtin_amdgcn_exp2f)
  return __builtin_amdgcn_exp2f(x);
#else
  return exp2f(x);
#endif
}

__device__ __forceinline__ float16v mfma16(uv4 a, uv4 b, float16v c) {
  return __builtin_amdgcn_mfma_f32_32x32x16_f16(
      __builtin_bit_cast(half8, a), __builtin_bit_cast(half8, b), c, 0, 0, 0);
}

// ---------------------------------------------------------------------------
// K0: one-time weight prep. W_frag[(ks*2+hi)*96 + o][e] = W[o][8*hi+16*ks+e]
// (f16, q-rows pre-scaled by log2e). bias_f[96] f32 (bq scaled).
// ---------------------------------------------------------------------------
__global__ __launch_bounds__(256) void k_prep(
    const float* __restrict__ Wq, const float* __restrict__ bq,
    const float* __restrict__ Wk, const float* __restrict__ bk,
    const float* __restrict__ Wv, const float* __restrict__ bv,
    ushort* __restrict__ W_frag, float* __restrict__ bias_f)
{
  int idx = blockIdx.x * 256 + threadIdx.x;   // 24 blocks -> 6144
  if (idx < 6144) {
    int g = idx >> 3, e = idx & 7;
    int kshi = g / 96, o = g % 96;
    int ks = kshi >> 1, hi = kshi & 1;
    int c = 8 * hi + 16 * ks + e;
    float val = (o < 8)  ? Wq[o * 64 + c] * LOG2E
              : (o < 16) ? Wk[(o - 8) * 64 + c]
              : (o < 80) ? Wv[(o - 16) * 64 + c] : 0.f;
    W_frag[idx] = f2h(val);
  }
  if (blockIdx.x == 0 && threadIdx.x < 96) {
    int t = threadIdx.x;
    bias_f[t] = (t < 8) ? bq[t] * LOG2E : (t < 16) ? bk[t - 8] : (t < 80) ? bv[t - 16] : 0.f;
  }
}

// ---------------------------------------------------------------------------
// K1: FUSED proj + W-pass attention. One block per (b, h) row, 4 waves.
// Proj phase: MFMA from W_frag + plane-strided x loads -> acc.
// Epilogue: q,k -> qk_l LDS [w][24]; v -> V_l LDS (swizzled, attn-ready).
// Stores: v planes (read back from V_l), qT/kT pixel-major transposed.
// Attn phase: W-pass (no mask) straight from LDS -> oW, mW, sW.
// ---------------------------------------------------------------------------
__global__ __launch_bounds__(256, 4) void k_projW(
    const float* __restrict__ x, const ushort* __restrict__ W_frag,
    const float* __restrict__ bias_f,
    ushort* __restrict__ qT, ushort* __restrict__ kT,
    ushort* __restrict__ v,
    ushort* __restrict__ oW_, float* __restrict__ mW_, float* __restrict__ sW_)
{
  alignas(16) __shared__ uint V_l[64 * 64];      // 16KB swizzled [c][j]; reused as o_l
  alignas(16) __shared__ ushort qk_l[128 * 24];  // [w][24]: q ch 0..7, k ch 8..15
  __shared__ float bias_l[96];

  int t = threadIdx.x;
  int lane = t & 63, wv = t >> 6, hi = lane >> 5;
  int b = blockIdx.x >> 7, r = blockIdx.x & 127;
  if (t < 96) bias_l[t] = bias_f[t];

  int w = 32 * wv + (lane & 31);
  const float* xw = x + (size_t)(b * CC) * (HW * HW) + (size_t)r * HW + w;
  const size_t PL = (size_t)HW * HW;

  // ---- proj phase ----
  float16v acc0 = {}, acc1 = {}, acc2 = {};
  #pragma unroll
  for (int ks = 0; ks < 4; ++ks) {
    int c0 = 8 * hi + 16 * ks;
    uint bx[4];
    #pragma unroll
    for (int e2 = 0; e2 < 4; ++e2) {
      float f0 = xw[(size_t)(c0 + 2 * e2) * PL];
      float f1 = xw[(size_t)(c0 + 2 * e2 + 1) * PL];
      bx[e2] = packh2(f0, f1);
    }
    uv4 Bx = {bx[0], bx[1], bx[2], bx[3]};
    const ushort* wf = W_frag + (size_t)(ks * 2 + hi) * 96 * 8;
    uv4 a0 = *(const uv4*)(wf + (lane & 31) * 8);
    uv4 a1 = *(const uv4*)(wf + ((lane & 31) + 32) * 8);
    uv4 a2 = *(const uv4*)(wf + ((lane & 31) + 64) * 8);
    acc0 = mfma16(a0, Bx, acc0);
    acc1 = mfma16(a1, Bx, acc1);
    acc2 = mfma16(a2, Bx, acc2);
  }
  __syncthreads();   // bias_l ready; LDS free

  // ---- epilogue: q,k -> qk_l; v -> V_l swizzled ----
  #pragma unroll
  for (int reg = 0; reg < 16; ++reg) {
    int orow = (reg & 3) + 8 * (reg >> 2) + 4 * hi;   // 0..31
    float v0 = acc0[reg] + bias_l[orow];
    if (orow < 16) {
      qk_l[w * 24 + orow] = f2h(v0);
    } else {
      int c = orow - 16;   // v ch 0..15
      *(ushort*)((char*)V_l + c * 256 + ((2 * w) ^ ((c & 15) << 4))) = f2h(v0);
    }
    int c1 = orow + 16;    // v ch 16..47
    *(ushort*)((char*)V_l + c1 * 256 + ((2 * w) ^ ((c1 & 15) << 4))) =
        f2h(acc1[reg] + bias_l[orow + 32]);
    if (orow < 16) {
      int c2_ = orow + 48; // v ch 48..63
      *(ushort*)((char*)V_l + c2_ * 256 + ((2 * w) ^ ((c2_ & 15) << 4))) =
          f2h(acc2[reg] + bias_l[orow + 64]);
    }
  }
  __syncthreads();

  // ---- global stores: v planes (from V_l), qT/kT transposed ----
  ushort* vb = v + (size_t)(b * CC) * PL + (size_t)r * HW;
  #pragma unroll
  for (int i = 0; i < 4; ++i) {
    int idx = t + 256 * i; int c = idx >> 4, j8 = idx & 15;
    uv4 val = *(const uv4*)((const char*)V_l + c * 256 + ((16 * j8) ^ ((c & 15) << 4)));
    *(uv4*)(vb + (size_t)c * PL + j8 * 8) = val;
  }
  {
    int pix = t & 127, isk = t >> 7;
    uv4 val = *(const uv4*)&qk_l[pix * 24 + isk * 8];
    ushort* dstt = (isk ? kT : qT) + ((size_t)(b * HW + pix) * HW + r) * 8;
    *(uv4*)dstt = val;
  }

  // ---- W-pass attention (no mask) ----
  int qg = w;
  uv4 Bq = {0, 0, 0, 0};
  uv4 ka[4] = {{0,0,0,0}, {0,0,0,0}, {0,0,0,0}, {0,0,0,0}};
  if (hi == 0) {
    Bq = *(const uv4*)&qk_l[qg * 24];
    #pragma unroll
    for (int mt = 0; mt < 4; ++mt)
      ka[mt] = *(const uv4*)&qk_l[((lane & 31) + 32 * mt) * 24 + 8];
  }

  float16v e[4];
  #pragma unroll
  for (int mt = 0; mt < 4; ++mt) {
    float16v z = {};
    e[mt] = mfma16(ka[mt], Bq, z);
  }

  float m = -INFINITY;
  #pragma unroll
  for (int mt = 0; mt < 4; ++mt)
    #pragma unroll
    for (int reg = 0; reg < 16; reg += 2)
      m = fmaxf(m, fmaxf(e[mt][reg], e[mt][reg + 1]));
  m = fmaxf(m, __shfl_xor(m, 32));

  float s0 = 0.f, s1 = 0.f, s2 = 0.f, s3 = 0.f;
  #pragma unroll
  for (int mt = 0; mt < 4; ++mt) {
    #pragma unroll
    for (int reg = 0; reg < 16; reg += 4) {
      float p0 = fexp2(e[mt][reg + 0] - m);
      float p1 = fexp2(e[mt][reg + 1] - m);
      float p2 = fexp2(e[mt][reg + 2] - m);
      float p3 = fexp2(e[mt][reg + 3] - m);
      e[mt][reg + 0] = p0; e[mt][reg + 1] = p1;
      e[mt][reg + 2] = p2; e[mt][reg + 3] = p3;
      s0 += p0; s1 += p1; s2 += p2; s3 += p3;
    }
  }
  float s = (s0 + s1) + (s2 + s3);
  s += __shfl_xor(s, 32);
  if (lane < 32) {
    mW_[(size_t)blockIdx.x * HW + qg] = m;
    sW_[(size_t)blockIdx.x * HW + qg] = s;
  }

  float16v pacc0 = {}, pacc1 = {};
  #pragma unroll
  for (int s8 = 0; s8 < 8; ++s8) {
    int mt = s8 >> 1, hf = s8 & 1;
    float p0 = e[mt][8 * hf + 0], p1 = e[mt][8 * hf + 1];
    float p2 = e[mt][8 * hf + 2], p3 = e[mt][8 * hf + 3];
    float p4 = e[mt][8 * hf + 4], p5 = e[mt][8 * hf + 5];
    float p6 = e[mt][8 * hf + 6], p7 = e[mt][8 * hf + 7];
    uint X = packh2(p0, p1), Y = packh2(p2, p3), Z = packh2(p4, p5), Wp = packh2(p6, p7);
    uint Xs = __shfl_xor(X, 32), Ys = __shfl_xor(Y, 32);
    uint Zs = __shfl_xor(Z, 32), Ws = __shfl_xor(Wp, 32);
    uv4 Bp;
    Bp[0] = (hi == 0) ? X  : Zs;
    Bp[1] = (hi == 0) ? Y  : Ws;
    Bp[2] = (hi == 0) ? Xs : Z;
    Bp[3] = (hi == 0) ? Ys : Wp;
    #pragma unroll
    for (int ct = 0; ct < 2; ++ct) {
      int c = (lane & 31) + 32 * ct;
      uint byteoff = c * 256 + ((16 * (hi + 2 * s8)) ^ ((c & 15) << 4));
      uv4 va = *(const uv4*)((const char*)V_l + byteoff);
      if (ct == 0) pacc0 = mfma16(va, Bp, pacc0);
      else         pacc1 = mfma16(va, Bp, pacc1);
    }
  }

  __syncthreads();
  ushort* o_l = (ushort*)V_l;
  #pragma unroll
  for (int reg = 0; reg < 16; ++reg) {
    int c = (reg & 3) + 8 * (reg >> 2) + 4 * hi;
    o_l[(c +  0) * 128 + w] = f2h(pacc0[reg]);
    o_l[(c + 32) * 128 + w] = f2h(pacc1[reg]);
  }
  __syncthreads();
  ushort* ob = oW_ + (size_t)(b * CC) * PL + (size_t)r * HW;
  #pragma unroll
  for (int i = 0; i < 4; ++i) {
    int idx = t + 256 * i; int c = idx >> 4, w8 = idx & 15;
    *(uv4*)(ob + (size_t)c * PL + w8 * 8) = *(const uv4*)&o_l[c * 128 + w8 * 8];
  }
}

// ---------------------------------------------------------------------------
// K2: v -> vT plane transposes.
// ---------------------------------------------------------------------------
__global__ __launch_bounds__(256) void k_transpose_v(const ushort* __restrict__ v,
                                                     ushort* __restrict__ vT)
{
  __shared__ ushort tl[128 * 130];
  int t = threadIdx.x;
  size_t base = (size_t)blockIdx.x * (HW * HW);
  const uint* ip = (const uint*)(v + base);
  uint* op = (uint*)(vT + base);
  int c2 = t & 63;
  int r0 = t >> 6;
  for (int it = 0; it < 32; ++it) {
    int r = it * 4 + r0;
    uint val = ip[r * 64 + c2];
    *(uint*)&tl[r * 130 + c2 * 2] = val;
  }
  __syncthreads();
  for (int it = 0; it < 32; ++it) {
    int wcol = it * 4 + r0;
    int hh = c2 * 2;
    uint lo = tl[hh * 130 + wcol];
    uint hi = tl[(hh + 1) * 130 + wcol];
    op[wcol * 64 + c2] = lo | (hi << 16);
  }
}

// ---------------------------------------------------------------------------
// K3: H-pass attention (diag mask). Grid 2048 = (b, column r). Reads
// qT/kT pixel-major, vT planes. Softmax exp2 domain. Plain stores.
// ---------------------------------------------------------------------------
__global__ __launch_bounds__(256, 4) void k_attnH(
    const ushort* __restrict__ qT, const ushort* __restrict__ kT,
    const ushort* __restrict__ vT,
    ushort* __restrict__ oH_, float* __restrict__ mH_, float* __restrict__ sH_)
{
  alignas(16) __shared__ uint V_l[64 * 64];   // 16KB, [c][j] swizzled

  int t = threadIdx.x;
  int lane = t & 63, wv = t >> 6;
  int hi = lane >> 5;
  int bid = blockIdx.x;
  int b = bid >> 7, r = bid & 127;
  size_t plane32 = (size_t)(HW * HW) / 2;
  size_t pixbase = (size_t)(b * HW + r) * HW * 8;

  int qg = 32 * wv + (lane & 31);
  uv4 Bq = {0, 0, 0, 0};
  uv4 ka[4] = {{0,0,0,0}, {0,0,0,0}, {0,0,0,0}, {0,0,0,0}};
  if (hi == 0) {
    Bq = *(const uv4*)(qT + pixbase + (size_t)qg * 8);
    #pragma unroll
    for (int mt = 0; mt < 4; ++mt)
      ka[mt] = *(const uv4*)(kT + pixbase + (size_t)((lane & 31) + 32 * mt) * 8);
  }

  const uint* vrow = (const uint*)vT + (size_t)(b * CC) * plane32 + (size_t)r * 64;
  #pragma unroll
  for (int i = 0; i < 4; ++i) {
    int idx = t + 256 * i; int c = idx >> 4, j4 = idx & 15;
    uv4 val = *(const uv4*)(vrow + (size_t)c * plane32 + 4 * j4);
    uint byteoff = c * 256 + ((16 * j4) ^ ((c & 15) << 4));
    *(uv4*)((char*)V_l + byteoff) = val;
  }
  __syncthreads();

  float16v e[4];
  #pragma unroll
  for (int mt = 0; mt < 4; ++mt) {
    float16v z = {};
    e[mt] = mfma16(ka[mt], Bq, z);
  }

  #pragma unroll
  for (int mt = 0; mt < 4; ++mt)
    #pragma unroll
    for (int reg = 0; reg < 16; ++reg) {
      int key = 32 * mt + ((reg & 3) + 8 * (reg >> 2) + 4 * hi);
      e[mt][reg] = (key == qg) ? -INFINITY : e[mt][reg];
    }

  float m = -INFINITY;
  #pragma unroll
  for (int mt = 0; mt < 4; ++mt)
    #pragma unroll
    for (int reg = 0; reg < 16; reg += 2)
      m = fmaxf(m, fmaxf(e[mt][reg], e[mt][reg + 1]));
  m = fmaxf(m, __shfl_xor(m, 32));

  float s0 = 0.f, s1 = 0.f, s2 = 0.f, s3 = 0.f;
  #pragma unroll
  for (int mt = 0; mt < 4; ++mt) {
    #pragma unroll
    for (int reg = 0; reg < 16; reg += 4) {
      float p0 = fexp2(e[mt][reg + 0] - m);
      float p1 = fexp2(e[mt][reg + 1] - m);
      float p2 = fexp2(e[mt][reg + 2] - m);
      float p3 = fexp2(e[mt][reg + 3] - m);
      e[mt][reg + 0] = p0; e[mt][reg + 1] = p1;
      e[mt][reg + 2] = p2; e[mt][reg + 3] = p3;
      s0 += p0; s1 += p1; s2 += p2; s3 += p3;
    }
  }
  float s = (s0 + s1) + (s2 + s3);
  s += __shfl_xor(s, 32);
  if (lane < 32) {
    mH_[(size_t)bid * HW + qg] = m;
    sH_[(size_t)bid * HW + qg] = s;
  }

  float16v acc0 = {}, acc1 = {};
  #pragma unroll
  for (int s8 = 0; s8 < 8; ++s8) {
    int mt = s8 >> 1, hf = s8 & 1;
    float p0 = e[mt][8 * hf + 0], p1 = e[mt][8 * hf + 1];
    float p2 = e[mt][8 * hf + 2], p3 = e[mt][8 * hf + 3];
    float p4 = e[mt][8 * hf + 4], p5 = e[mt][8 * hf + 5];
    float p6 = e[mt][8 * hf + 6], p7 = e[mt][8 * hf + 7];
    uint X = packh2(p0, p1), Y = packh2(p2, p3), Z = packh2(p4, p5), Wp = packh2(p6, p7);
    uint Xs = __shfl_xor(X, 32), Ys = __shfl_xor(Y, 32);
    uint Zs = __shfl_xor(Z, 32), Ws = __shfl_xor(Wp, 32);
    uv4 Bp;
    Bp[0] = (hi == 0) ? X  : Zs;
    Bp[1] = (hi == 0) ? Y  : Ws;
    Bp[2] = (hi == 0) ? Xs : Z;
    Bp[3] = (hi == 0) ? Ys : Wp;
    #pragma unroll
    for (int ct = 0; ct < 2; ++ct) {
      int c = (lane & 31) + 32 * ct;
      uint byteoff = c * 256 + ((16 * (hi + 2 * s8)) ^ ((c & 15) << 4));
      uv4 va = *(const uv4*)((const char*)V_l + byteoff);
      if (ct == 0) acc0 = mfma16(va, Bp, acc0);
      else         acc1 = mfma16(va, Bp, acc1);
    }
  }

  __syncthreads();
  ushort* o_l = (ushort*)V_l;
  int w = 32 * wv + (lane & 31);
  #pragma unroll
  for (int reg = 0; reg < 16; ++reg) {
    int c = (reg & 3) + 8 * (reg >> 2) + 4 * hi;
    o_l[(c +  0) * 128 + w] = f2h(acc0[reg]);
    o_l[(c + 32) * 128 + w] = f2h(acc1[reg]);
  }
  __syncthreads();
  ushort* ob = oH_ + (size_t)(b * CC) * (HW * HW) + (size_t)r * HW;
  #pragma unroll
  for (int i = 0; i < 4; ++i) {
    int idx = t + 256 * i; int c = idx >> 4, w8 = idx & 15;
    *(uv4*)(ob + (size_t)c * (HW * HW) + w8 * 8) = *(const uv4*)&o_l[c * 128 + w8 * 8];
  }
}

// ---------------------------------------------------------------------------
// K4a: per-pixel alphas (f16), exp2 domain. aHT [b][w][h]; aW [b][h][w].
// ---------------------------------------------------------------------------
__global__ __launch_bounds__(256) void k_alpha(
    const float* __restrict__ mH, const float* __restrict__ sH,
    const float* __restrict__ mW, const float* __restrict__ sW,
    ushort* __restrict__ aHT, ushort* __restrict__ aWn)
{
  __shared__ float mw_l[128 * 9], sw_l[128 * 9];   // [h][w]
  __shared__ ushort aw_l[128 * 10];                // [h][w]
  int t = threadIdx.x;
  int b = blockIdx.x >> 4, ws = blockIdx.x & 15;
  int w0 = ws * 8;
  const int PL = HW * HW;

  #pragma unroll
  for (int i = 0; i < 4; ++i) {
    int p = t + 256 * i;
    int w = p & 7, h = p >> 3;
    mw_l[h * 9 + w] = mW[(size_t)b * PL + h * HW + w0 + w];
    sw_l[h * 9 + w] = sW[(size_t)b * PL + h * HW + w0 + w];
  }
  __syncthreads();
  #pragma unroll
  for (int i = 0; i < 4; ++i) {
    int p = t + 256 * i;
    int h = p & 127, w = p >> 7;
    size_t tidx = (size_t)b * PL + (size_t)(w0 + w) * HW + h;
    float mh = mH[tidx], sh = sH[tidx];
    float mw = mw_l[h * 9 + w], sw = sw_l[h * 9 + w];
    float mm = fmaxf(mh, mw);
    float eh = fexp2(mh - mm), ew = fexp2(mw - mm);
    float inv = 1.f / (sh * eh + sw * ew);
    aHT[tidx] = f2h(eh * inv);
    aw_l[h * 10 + w] = f2h(ew * inv);
  }
  __syncthreads();
  #pragma unroll
  for (int i = 0; i < 4; ++i) {
    int p = t + 256 * i;
    int w = p & 7, h = p >> 3;
    aWn[(size_t)b * PL + (size_t)h * HW + w0 + w] = aw_l[h * 10 + w];
  }
}

// ---------------------------------------------------------------------------
// K4b: merge (round-10 version, plain loads/stores). Block = (b, 2-ch group,
// 32-w stripe). Grid 2048. ONE barrier.
// ---------------------------------------------------------------------------
__global__ __launch_bounds__(256) void k_merge(
    const ushort* __restrict__ oHT, const ushort* __restrict__ oW,
    const ushort* __restrict__ aHT, const ushort* __restrict__ aWn,
    const float* __restrict__ x, const float* __restrict__ gamma,
    float* __restrict__ out)
{
  alignas(16) __shared__ ushort otile[2 * 32 * 132];  // [ch][w][h], h-stride 132
  int t = threadIdx.x;
  int bid = blockIdx.x;
  int wsel = bid & 3, cg = (bid >> 2) & 31, b = bid >> 7;
  int w0 = wsel * 32;
  float g = gamma[0];
  const int PL = HW * HW;

  #pragma unroll
  for (int i = 0; i < 4; ++i) {
    int p = t + 256 * i;
    int ch = p >> 9, rest = p & 511;
    int w = rest >> 4, hg = rest & 15;
    size_t cbase = (size_t)(b * CC + cg * 2 + ch) * PL;
    uv4 ov = *(const uv4*)(oHT + cbase + (size_t)(w0 + w) * HW + hg * 8);
    uv4 av = *(const uv4*)(aHT + (size_t)b * PL + (size_t)(w0 + w) * HW + hg * 8);
    uv4 res;
    #pragma unroll
    for (int jj = 0; jj < 4; ++jj) {
      h2 o2 = __builtin_bit_cast(h2, ov[jj]);
      h2 a2 = __builtin_bit_cast(h2, av[jj]);
      res[jj] = __builtin_bit_cast(uint, o2 * a2);
    }
    *(uv4*)&otile[(ch * 32 + w) * 132 + hg * 8] = res;
  }
  __syncthreads();

  #pragma unroll
  for (int ch = 0; ch < 2; ++ch) {
    size_t cbase = (size_t)(b * CC + cg * 2 + ch) * PL;
    const ushort* otc = &otile[ch * 32 * 132];
    #pragma unroll
    for (int i = 0; i < 2; ++i) {
      int p = t + 256 * i;
      int w4 = p & 7, hh2 = p >> 3;
      float th0[4], th1[4];
      #pragma unroll
      for (int j = 0; j < 4; ++j) {
        uint pk = *(const uint*)&otc[(4 * w4 + j) * 132 + 2 * hh2];
        th0[j] = h2f((ushort)(pk & 0xffff));
        th1[j] = h2f((ushort)(pk >> 16));
      }
      #pragma unroll
      for (int rr = 0; rr < 2; ++rr) {
        int hh = 2 * hh2 + rr;
        const float* th = rr ? th1 : th0;
        size_t base = cbase + (size_t)hh * HW + w0 + 4 * w4;
        size_t abase = (size_t)b * PL + (size_t)hh * HW + w0 + 4 * w4;
        uint2 aw2 = *(const uint2*)(aWn + abase);
        uint2 ow2 = *(const uint2*)(oW + base);
        float4 xv = *(const float4*)(x + base);
        float4 res;
        res.x = g * (th[0] + h2f((ushort)(ow2.x & 0xffff)) * h2f((ushort)(aw2.x & 0xffff))) + xv.x;
        res.y = g * (th[1] + h2f((ushort)(ow2.x >> 16))    * h2f((ushort)(aw2.x >> 16)))    + xv.y;
        res.z = g * (th[2] + h2f((ushort)(ow2.y & 0xffff)) * h2f((ushort)(aw2.y & 0xffff))) + xv.z;
        res.w = g * (th[3] + h2f((ushort)(ow2.y >> 16))    * h2f((ushort)(aw2.y >> 16)))    + xv.w;
        *(float4*)(out + base) = res;
      }
    }
  }
}

extern "C" void kernel_launch(void* const* d_in, const int* in_sizes, int n_in,
                              void* d_out, int out_size, void* d_ws, size_t ws_size,
                              hipStream_t stream)
{
  const float* x     = (const float*)d_in[0];
  const float* Wq    = (const float*)d_in[1];
  const float* bq    = (const float*)d_in[2];
  const float* Wk    = (const float*)d_in[3];
  const float* bk    = (const float*)d_in[4];
  const float* Wv    = (const float*)d_in[5];
  const float* bv    = (const float*)d_in[6];
  const float* gamma = (const float*)d_in[7];
  float* out = (float*)d_out;

  char* w = (char*)d_ws;
  size_t np = (size_t)NB * HW * HW;
  ushort* W_frag = (ushort*)w; w += 6144 * 2;
  float*  bias_f = (float*)w;  w += 96 * 4 + 320;   // keep 16B alignment
  ushort* qT  = (ushort*)w;  w += np * 8 * 2;   // pixel-major 8ch transposed
  ushort* kT  = (ushort*)w;  w += np * 8 * 2;
  ushort* v   = (ushort*)w;  w += np * CC * 2;
  ushort* vT  = (ushort*)w;  w += np * CC * 2;
  ushort* oW  = (ushort*)w;  w += np * CC * 2;
  ushort* oHT = (ushort*)w;  w += np * CC * 2;
  float* mW = (float*)w;  w += np * 4;
  float* sW = (float*)w;  w += np * 4;
  float* mH = (float*)w;  w += np * 4;
  float* sH = (float*)w;  w += np * 4;
  ushort* aHT = (ushort*)w; w += np * 2;
  ushort* aWn = (ushort*)w; w += np * 2;
  if ((size_t)(w - (char*)d_ws) > ws_size) return;

  k_prep<<<24, 256, 0, stream>>>(Wq, bq, Wk, bk, Wv, bv, W_frag, bias_f);
  k_projW<<<NB * HW, 256, 0, stream>>>(x, W_frag, bias_f, qT, kT, v, oW, mW, sW);
  k_transpose_v<<<NB * CC, 256, 0, stream>>>(v, vT);
  k_attnH<<<NB * HW, 256, 0, stream>>>(qT, kT, vT, oHT, mH, sH);
  k_alpha<<<NB * 16, 256, 0, stream>>>(mH, sH, mW, sW, aHT, aWn);
  k_merge<<<NB * 32 * 4, 256, 0, stream>>>(oHT, oW, aHT, aWn, x, gamma, out);
}

// Round 14
// 103.267 us; speedup vs baseline: 1.1980x; 1.0404x over previous
//
#include <hip/hip_runtime.h>

#define HW 128      // H == W
#define CC 64       // C
#define NB 16       // B
#define LOG2E 1.44269504088896f

typedef _Float16 h1;
typedef _Float16 h2 __attribute__((ext_vector_type(2)));
typedef _Float16 half8 __attribute__((ext_vector_type(8)));
typedef float float16v __attribute__((ext_vector_type(16)));
typedef uint uv4 __attribute__((ext_vector_type(4)));

__device__ __forceinline__ uint packh2(float a, float b) {
#if __has_builtin(__builtin_amdgcn_cvt_pkrtz)
  return __builtin_bit_cast(uint, __builtin_amdgcn_cvt_pkrtz(a, b));
#else
  h2 v; v[0] = (h1)a; v[1] = (h1)b; return __builtin_bit_cast(uint, v);
#endif
}
__device__ __forceinline__ ushort f2h(float a) { h1 v = (h1)a; return __builtin_bit_cast(ushort, v); }
__device__ __forceinline__ float  h2f(ushort a) { return (float)__builtin_bit_cast(h1, a); }

__device__ __forceinline__ float fexp2(float x) {
#if __has_builtin(__builtin_amdgcn_exp2f)
  return __builtin_amdgcn_exp2f(x);
#else
  return exp2f(x);
#endif
}

__device__ __forceinline__ float16v mfma16(uv4 a, uv4 b, float16v c) {
  return __builtin_amdgcn_mfma_f32_32x32x16_f16(
      __builtin_bit_cast(half8, a), __builtin_bit_cast(half8, b), c, 0, 0, 0);
}

// ---------------------------------------------------------------------------
// K0: one-time weight prep. W_frag[(ks*2+hi)*96 + o][e] = W[o][8*hi+16*ks+e]
// (f16, q-rows pre-scaled by log2e). bias_f[96] f32 (bq scaled).
// ---------------------------------------------------------------------------
__global__ __launch_bounds__(256) void k_prep(
    const float* __restrict__ Wq, const float* __restrict__ bq,
    const float* __restrict__ Wk, const float* __restrict__ bk,
    const float* __restrict__ Wv, const float* __restrict__ bv,
    ushort* __restrict__ W_frag, float* __restrict__ bias_f)
{
  int idx = blockIdx.x * 256 + threadIdx.x;   // 24 blocks -> 6144
  if (idx < 6144) {
    int g = idx >> 3, e = idx & 7;
    int kshi = g / 96, o = g % 96;
    int ks = kshi >> 1, hi = kshi & 1;
    int c = 8 * hi + 16 * ks + e;
    float val = (o < 8)  ? Wq[o * 64 + c] * LOG2E
              : (o < 16) ? Wk[(o - 8) * 64 + c]
              : (o < 80) ? Wv[(o - 16) * 64 + c] : 0.f;
    W_frag[idx] = f2h(val);
  }
  if (blockIdx.x == 0 && threadIdx.x < 96) {
    int t = threadIdx.x;
    bias_f[t] = (t < 8) ? bq[t] * LOG2E : (t < 16) ? bk[t - 8] : (t < 80) ? bv[t - 16] : 0.f;
  }
}

// ---------------------------------------------------------------------------
// K1: FUSED proj + W-pass attention. One block per (b, h) row, 4 waves.
// All 32 x scalars preloaded (sched_barrier-pinned), then pack+MFMA.
// Epilogue: q,k -> qk_l LDS; v -> V_l LDS (swizzled). Stores v planes,
// qT/kT pixel-major transposed. W-pass attention from LDS -> oW, mW, sW.
// ---------------------------------------------------------------------------
__global__ __launch_bounds__(256, 4) void k_projW(
    const float* __restrict__ x, const ushort* __restrict__ W_frag,
    const float* __restrict__ bias_f,
    ushort* __restrict__ qT, ushort* __restrict__ kT,
    ushort* __restrict__ v,
    ushort* __restrict__ oW_, float* __restrict__ mW_, float* __restrict__ sW_)
{
  alignas(16) __shared__ uint V_l[64 * 64];      // 16KB swizzled [c][j]; reused as o_l
  alignas(16) __shared__ ushort qk_l[128 * 24];  // [w][24]: q ch 0..7, k ch 8..15
  __shared__ float bias_l[96];

  int t = threadIdx.x;
  int lane = t & 63, wv = t >> 6, hi = lane >> 5;
  int b = blockIdx.x >> 7, r = blockIdx.x & 127;
  if (t < 96) bias_l[t] = bias_f[t];

  int w = 32 * wv + (lane & 31);
  const float* xw = x + (size_t)(b * CC) * (HW * HW) + (size_t)r * HW + w;
  const size_t PL = (size_t)HW * HW;

  // ---- proj phase: preload ALL x values (pinned), then pack + MFMA ----
  float xv[32];
  #pragma unroll
  for (int ks = 0; ks < 4; ++ks) {
    int c0 = 8 * hi + 16 * ks;
    #pragma unroll
    for (int e = 0; e < 8; ++e)
      xv[ks * 8 + e] = xw[(size_t)(c0 + e) * PL];
  }
  __builtin_amdgcn_sched_barrier(0);

  float16v acc0 = {}, acc1 = {}, acc2 = {};
  #pragma unroll
  for (int ks = 0; ks < 4; ++ks) {
    uv4 Bx;
    #pragma unroll
    for (int e2 = 0; e2 < 4; ++e2)
      Bx[e2] = packh2(xv[ks * 8 + 2 * e2], xv[ks * 8 + 2 * e2 + 1]);
    const ushort* wf = W_frag + (size_t)(ks * 2 + hi) * 96 * 8;
    uv4 a0 = *(const uv4*)(wf + (lane & 31) * 8);
    uv4 a1 = *(const uv4*)(wf + ((lane & 31) + 32) * 8);
    uv4 a2 = *(const uv4*)(wf + ((lane & 31) + 64) * 8);
    acc0 = mfma16(a0, Bx, acc0);
    acc1 = mfma16(a1, Bx, acc1);
    acc2 = mfma16(a2, Bx, acc2);
  }
  __syncthreads();   // bias_l ready; LDS free

  // ---- epilogue: q,k -> qk_l; v -> V_l swizzled ----
  #pragma unroll
  for (int reg = 0; reg < 16; ++reg) {
    int orow = (reg & 3) + 8 * (reg >> 2) + 4 * hi;   // 0..31
    float v0 = acc0[reg] + bias_l[orow];
    if (orow < 16) {
      qk_l[w * 24 + orow] = f2h(v0);
    } else {
      int c = orow - 16;   // v ch 0..15
      *(ushort*)((char*)V_l + c * 256 + ((2 * w) ^ ((c & 15) << 4))) = f2h(v0);
    }
    int c1 = orow + 16;    // v ch 16..47
    *(ushort*)((char*)V_l + c1 * 256 + ((2 * w) ^ ((c1 & 15) << 4))) =
        f2h(acc1[reg] + bias_l[orow + 32]);
    if (orow < 16) {
      int c2_ = orow + 48; // v ch 48..63
      *(ushort*)((char*)V_l + c2_ * 256 + ((2 * w) ^ ((c2_ & 15) << 4))) =
          f2h(acc2[reg] + bias_l[orow + 64]);
    }
  }
  __syncthreads();

  // ---- global stores: v planes (from V_l), qT/kT transposed ----
  ushort* vb = v + (size_t)(b * CC) * PL + (size_t)r * HW;
  #pragma unroll
  for (int i = 0; i < 4; ++i) {
    int idx = t + 256 * i; int c = idx >> 4, j8 = idx & 15;
    uv4 val = *(const uv4*)((const char*)V_l + c * 256 + ((16 * j8) ^ ((c & 15) << 4)));
    *(uv4*)(vb + (size_t)c * PL + j8 * 8) = val;
  }
  {
    int pix = t & 127, isk = t >> 7;
    uv4 val = *(const uv4*)&qk_l[pix * 24 + isk * 8];
    ushort* dstt = (isk ? kT : qT) + ((size_t)(b * HW + pix) * HW + r) * 8;
    *(uv4*)dstt = val;
  }

  // ---- W-pass attention (no mask) ----
  int qg = w;
  uv4 Bq = {0, 0, 0, 0};
  uv4 ka[4] = {{0,0,0,0}, {0,0,0,0}, {0,0,0,0}, {0,0,0,0}};
  if (hi == 0) {
    Bq = *(const uv4*)&qk_l[qg * 24];
    #pragma unroll
    for (int mt = 0; mt < 4; ++mt)
      ka[mt] = *(const uv4*)&qk_l[((lane & 31) + 32 * mt) * 24 + 8];
  }

  float16v e[4];
  #pragma unroll
  for (int mt = 0; mt < 4; ++mt) {
    float16v z = {};
    e[mt] = mfma16(ka[mt], Bq, z);
  }

  float m = -INFINITY;
  #pragma unroll
  for (int mt = 0; mt < 4; ++mt)
    #pragma unroll
    for (int reg = 0; reg < 16; reg += 2)
      m = fmaxf(m, fmaxf(e[mt][reg], e[mt][reg + 1]));
  m = fmaxf(m, __shfl_xor(m, 32));

  float s0 = 0.f, s1 = 0.f, s2 = 0.f, s3 = 0.f;
  #pragma unroll
  for (int mt = 0; mt < 4; ++mt) {
    #pragma unroll
    for (int reg = 0; reg < 16; reg += 4) {
      float p0 = fexp2(e[mt][reg + 0] - m);
      float p1 = fexp2(e[mt][reg + 1] - m);
      float p2 = fexp2(e[mt][reg + 2] - m);
      float p3 = fexp2(e[mt][reg + 3] - m);
      e[mt][reg + 0] = p0; e[mt][reg + 1] = p1;
      e[mt][reg + 2] = p2; e[mt][reg + 3] = p3;
      s0 += p0; s1 += p1; s2 += p2; s3 += p3;
    }
  }
  float s = (s0 + s1) + (s2 + s3);
  s += __shfl_xor(s, 32);
  if (lane < 32) {
    mW_[(size_t)blockIdx.x * HW + qg] = m;
    sW_[(size_t)blockIdx.x * HW + qg] = s;
  }

  float16v pacc0 = {}, pacc1 = {};
  #pragma unroll
  for (int s8 = 0; s8 < 8; ++s8) {
    int mt = s8 >> 1, hf = s8 & 1;
    float p0 = e[mt][8 * hf + 0], p1 = e[mt][8 * hf + 1];
    float p2 = e[mt][8 * hf + 2], p3 = e[mt][8 * hf + 3];
    float p4 = e[mt][8 * hf + 4], p5 = e[mt][8 * hf + 5];
    float p6 = e[mt][8 * hf + 6], p7 = e[mt][8 * hf + 7];
    uint X = packh2(p0, p1), Y = packh2(p2, p3), Z = packh2(p4, p5), Wp = packh2(p6, p7);
    uint Xs = __shfl_xor(X, 32), Ys = __shfl_xor(Y, 32);
    uint Zs = __shfl_xor(Z, 32), Ws = __shfl_xor(Wp, 32);
    uv4 Bp;
    Bp[0] = (hi == 0) ? X  : Zs;
    Bp[1] = (hi == 0) ? Y  : Ws;
    Bp[2] = (hi == 0) ? Xs : Z;
    Bp[3] = (hi == 0) ? Ys : Wp;
    #pragma unroll
    for (int ct = 0; ct < 2; ++ct) {
      int c = (lane & 31) + 32 * ct;
      uint byteoff = c * 256 + ((16 * (hi + 2 * s8)) ^ ((c & 15) << 4));
      uv4 va = *(const uv4*)((const char*)V_l + byteoff);
      if (ct == 0) pacc0 = mfma16(va, Bp, pacc0);
      else         pacc1 = mfma16(va, Bp, pacc1);
    }
  }

  __syncthreads();
  ushort* o_l = (ushort*)V_l;
  #pragma unroll
  for (int reg = 0; reg < 16; ++reg) {
    int c = (reg & 3) + 8 * (reg >> 2) + 4 * hi;
    o_l[(c +  0) * 128 + w] = f2h(pacc0[reg]);
    o_l[(c + 32) * 128 + w] = f2h(pacc1[reg]);
  }
  __syncthreads();
  ushort* ob = oW_ + (size_t)(b * CC) * PL + (size_t)r * HW;
  #pragma unroll
  for (int i = 0; i < 4; ++i) {
    int idx = t + 256 * i; int c = idx >> 4, w8 = idx & 15;
    *(uv4*)(ob + (size_t)c * PL + w8 * 8) = *(const uv4*)&o_l[c * 128 + w8 * 8];
  }
}

// ---------------------------------------------------------------------------
// K2: v -> vT plane transposes.
// ---------------------------------------------------------------------------
__global__ __launch_bounds__(256) void k_transpose_v(const ushort* __restrict__ v,
                                                     ushort* __restrict__ vT)
{
  __shared__ ushort tl[128 * 130];
  int t = threadIdx.x;
  size_t base = (size_t)blockIdx.x * (HW * HW);
  const uint* ip = (const uint*)(v + base);
  uint* op = (uint*)(vT + base);
  int c2 = t & 63;
  int r0 = t >> 6;
  for (int it = 0; it < 32; ++it) {
    int r = it * 4 + r0;
    uint val = ip[r * 64 + c2];
    *(uint*)&tl[r * 130 + c2 * 2] = val;
  }
  __syncthreads();
  for (int it = 0; it < 32; ++it) {
    int wcol = it * 4 + r0;
    int hh = c2 * 2;
    uint lo = tl[hh * 130 + wcol];
    uint hi = tl[(hh + 1) * 130 + wcol];
    op[wcol * 64 + c2] = lo | (hi << 16);
  }
}

// ---------------------------------------------------------------------------
// K3: H-pass attention (diag mask) + FUSED alpha. Grid 2048 = (b, column r).
// Loads mW/sW for its column early; computes alphaH/alphaW after softmax;
// pre-scales its output by alphaH; writes alphaW (f16, natural layout).
// No mH/sH round-trip.
// ---------------------------------------------------------------------------
__global__ __launch_bounds__(256, 4) void k_attnH(
    const ushort* __restrict__ qT, const ushort* __restrict__ kT,
    const ushort* __restrict__ vT,
    const float* __restrict__ mW_, const float* __restrict__ sW_,
    ushort* __restrict__ oH_, ushort* __restrict__ aWn)
{
  alignas(16) __shared__ uint V_l[64 * 64];   // 16KB, [c][j] swizzled

  int t = threadIdx.x;
  int lane = t & 63, wv = t >> 6;
  int hi = lane >> 5;
  int bid = blockIdx.x;
  int b = bid >> 7, r = bid & 127;
  size_t plane32 = (size_t)(HW * HW) / 2;
  const size_t PL = (size_t)HW * HW;
  size_t pixbase = (size_t)(b * HW + r) * HW * 8;

  int qg = 32 * wv + (lane & 31);
  uv4 Bq = {0, 0, 0, 0};
  uv4 ka[4] = {{0,0,0,0}, {0,0,0,0}, {0,0,0,0}, {0,0,0,0}};
  if (hi == 0) {
    Bq = *(const uv4*)(qT + pixbase + (size_t)qg * 8);
    #pragma unroll
    for (int mt = 0; mt < 4; ++mt)
      ka[mt] = *(const uv4*)(kT + pixbase + (size_t)((lane & 31) + 32 * mt) * 8);
  }
  // W-pass stats for pixel (h=qg, w=r): issued early, used after softmax
  float mw = mW_[(size_t)b * PL + (size_t)qg * HW + r];
  float sw = sW_[(size_t)b * PL + (size_t)qg * HW + r];

  const uint* vrow = (const uint*)vT + (size_t)(b * CC) * plane32 + (size_t)r * 64;
  #pragma unroll
  for (int i = 0; i < 4; ++i) {
    int idx = t + 256 * i; int c = idx >> 4, j4 = idx & 15;
    uv4 val = *(const uv4*)(vrow + (size_t)c * plane32 + 4 * j4);
    uint byteoff = c * 256 + ((16 * j4) ^ ((c & 15) << 4));
    *(uv4*)((char*)V_l + byteoff) = val;
  }
  __syncthreads();

  float16v e[4];
  #pragma unroll
  for (int mt = 0; mt < 4; ++mt) {
    float16v z = {};
    e[mt] = mfma16(ka[mt], Bq, z);
  }

  #pragma unroll
  for (int mt = 0; mt < 4; ++mt)
    #pragma unroll
    for (int reg = 0; reg < 16; ++reg) {
      int key = 32 * mt + ((reg & 3) + 8 * (reg >> 2) + 4 * hi);
      e[mt][reg] = (key == qg) ? -INFINITY : e[mt][reg];
    }

  float m = -INFINITY;
  #pragma unroll
  for (int mt = 0; mt < 4; ++mt)
    #pragma unroll
    for (int reg = 0; reg < 16; reg += 2)
      m = fmaxf(m, fmaxf(e[mt][reg], e[mt][reg + 1]));
  m = fmaxf(m, __shfl_xor(m, 32));

  float s0 = 0.f, s1 = 0.f, s2 = 0.f, s3 = 0.f;
  #pragma unroll
  for (int mt = 0; mt < 4; ++mt) {
    #pragma unroll
    for (int reg = 0; reg < 16; reg += 4) {
      float p0 = fexp2(e[mt][reg + 0] - m);
      float p1 = fexp2(e[mt][reg + 1] - m);
      float p2 = fexp2(e[mt][reg + 2] - m);
      float p3 = fexp2(e[mt][reg + 3] - m);
      e[mt][reg + 0] = p0; e[mt][reg + 1] = p1;
      e[mt][reg + 2] = p2; e[mt][reg + 3] = p3;
      s0 += p0; s1 += p1; s2 += p2; s3 += p3;
    }
  }
  float s = (s0 + s1) + (s2 + s3);
  s += __shfl_xor(s, 32);

  // fused alpha (exp2 domain): combine H stats (m,s) with W stats (mw,sw)
  float mm = fmaxf(m, mw);
  float eh = fexp2(m - mm), ew = fexp2(mw - mm);
  float inv = 1.f / (s * eh + sw * ew);
  float aH = eh * inv;
  if (hi == 0)
    aWn[(size_t)b * PL + (size_t)qg * HW + r] = f2h(ew * inv);

  float16v acc0 = {}, acc1 = {};
  #pragma unroll
  for (int s8 = 0; s8 < 8; ++s8) {
    int mt = s8 >> 1, hf = s8 & 1;
    float p0 = e[mt][8 * hf + 0], p1 = e[mt][8 * hf + 1];
    float p2 = e[mt][8 * hf + 2], p3 = e[mt][8 * hf + 3];
    float p4 = e[mt][8 * hf + 4], p5 = e[mt][8 * hf + 5];
    float p6 = e[mt][8 * hf + 6], p7 = e[mt][8 * hf + 7];
    uint X = packh2(p0, p1), Y = packh2(p2, p3), Z = packh2(p4, p5), Wp = packh2(p6, p7);
    uint Xs = __shfl_xor(X, 32), Ys = __shfl_xor(Y, 32);
    uint Zs = __shfl_xor(Z, 32), Ws = __shfl_xor(Wp, 32);
    uv4 Bp;
    Bp[0] = (hi == 0) ? X  : Zs;
    Bp[1] = (hi == 0) ? Y  : Ws;
    Bp[2] = (hi == 0) ? Xs : Z;
    Bp[3] = (hi == 0) ? Ys : Wp;
    #pragma unroll
    for (int ct = 0; ct < 2; ++ct) {
      int c = (lane & 31) + 32 * ct;
      uint byteoff = c * 256 + ((16 * (hi + 2 * s8)) ^ ((c & 15) << 4));
      uv4 va = *(const uv4*)((const char*)V_l + byteoff);
      if (ct == 0) acc0 = mfma16(va, Bp, acc0);
      else         acc1 = mfma16(va, Bp, acc1);
    }
  }

  __syncthreads();
  ushort* o_l = (ushort*)V_l;
  int w = 32 * wv + (lane & 31);
  #pragma unroll
  for (int reg = 0; reg < 16; ++reg) {
    int c = (reg & 3) + 8 * (reg >> 2) + 4 * hi;
    o_l[(c +  0) * 128 + w] = f2h(acc0[reg] * aH);
    o_l[(c + 32) * 128 + w] = f2h(acc1[reg] * aH);
  }
  __syncthreads();
  ushort* ob = oH_ + (size_t)(b * CC) * PL + (size_t)r * HW;
  #pragma unroll
  for (int i = 0; i < 4; ++i) {
    int idx = t + 256 * i; int c = idx >> 4, w8 = idx & 15;
    *(uv4*)(ob + (size_t)c * PL + w8 * 8) = *(const uv4*)&o_l[c * 128 + w8 * 8];
  }
}

// ---------------------------------------------------------------------------
// K4: merge. Block = (b, 2-ch group, 32-w stripe). Grid 2048. ONE barrier.
// oHT is already alphaH-scaled. Consume-phase x/oW/aW loads issued BEFORE
// the barrier (fence pins them) -> deep MLP in both phases.
// ---------------------------------------------------------------------------
__global__ __launch_bounds__(256) void k_merge(
    const ushort* __restrict__ oHT, const ushort* __restrict__ oW,
    const ushort* __restrict__ aWn,
    const float* __restrict__ x, const float* __restrict__ gamma,
    float* __restrict__ out)
{
  alignas(16) __shared__ ushort otile[2 * 32 * 132];  // [ch][w][h], h-stride 132
  int t = threadIdx.x;
  int bid = blockIdx.x;
  int wsel = bid & 3, cg = (bid >> 2) & 31, b = bid >> 7;
  int w0 = wsel * 32;
  float g = gamma[0];
  const int PL = HW * HW;

  // A: stage loads (pre-scaled oHT, coalesced along h)
  uv4 ov[4];
  #pragma unroll
  for (int i = 0; i < 4; ++i) {
    int p = t + 256 * i;
    int ch = p >> 9, rest = p & 511;
    int w = rest >> 4, hg = rest & 15;
    size_t cbase = (size_t)(b * CC + cg * 2 + ch) * PL;
    ov[i] = *(const uv4*)(oHT + cbase + (size_t)(w0 + w) * HW + hg * 8);
  }
  // B: consume-phase preloads — issued before the barrier so they CANNOT be
  // sunk below it; stay in flight under the stage phase + barrier.
  uint2 owp[8]; float4 xp[8]; uint2 awp[4];
  #pragma unroll
  for (int i = 0; i < 2; ++i) {
    int p = t + 256 * i;
    int w4 = p & 7, hh2 = p >> 3;
    #pragma unroll
    for (int rr = 0; rr < 2; ++rr) {
      int hh = 2 * hh2 + rr;
      size_t poff = (size_t)hh * HW + w0 + 4 * w4;
      awp[i * 2 + rr] = *(const uint2*)(aWn + (size_t)b * PL + poff);
      #pragma unroll
      for (int ch = 0; ch < 2; ++ch) {
        size_t base = (size_t)(b * CC + cg * 2 + ch) * PL + poff;
        owp[ch * 4 + i * 2 + rr] = *(const uint2*)(oW + base);
        xp[ch * 4 + i * 2 + rr]  = *(const float4*)(x + base);
      }
    }
  }
  // C: stage to LDS
  #pragma unroll
  for (int i = 0; i < 4; ++i) {
    int p = t + 256 * i;
    int ch = p >> 9, rest = p & 511;
    int w = rest >> 4, hg = rest & 15;
    *(uv4*)&otile[(ch * 32 + w) * 132 + hg * 8] = ov[i];
  }
  __syncthreads();

  // D: consume from registers + LDS
  #pragma unroll
  for (int ch = 0; ch < 2; ++ch) {
    size_t cbase = (size_t)(b * CC + cg * 2 + ch) * PL;
    const ushort* otc = &otile[ch * 32 * 132];
    #pragma unroll
    for (int i = 0; i < 2; ++i) {
      int p = t + 256 * i;
      int w4 = p & 7, hh2 = p >> 3;
      float th0[4], th1[4];
      #pragma unroll
      for (int j = 0; j < 4; ++j) {
        uint pk = *(const uint*)&otc[(4 * w4 + j) * 132 + 2 * hh2];
        th0[j] = h2f((ushort)(pk & 0xffff));
        th1[j] = h2f((ushort)(pk >> 16));
      }
      #pragma unroll
      for (int rr = 0; rr < 2; ++rr) {
        int hh = 2 * hh2 + rr;
        const float* th = rr ? th1 : th0;
        size_t base = cbase + (size_t)hh * HW + w0 + 4 * w4;
        uint2 aw2 = awp[i * 2 + rr];
        uint2 ow2 = owp[ch * 4 + i * 2 + rr];
        float4 xv = xp[ch * 4 + i * 2 + rr];
        float4 res;
        res.x = g * (th[0] + h2f((ushort)(ow2.x & 0xffff)) * h2f((ushort)(aw2.x & 0xffff))) + xv.x;
        res.y = g * (th[1] + h2f((ushort)(ow2.x >> 16))    * h2f((ushort)(aw2.x >> 16)))    + xv.y;
        res.z = g * (th[2] + h2f((ushort)(ow2.y & 0xffff)) * h2f((ushort)(aw2.y & 0xffff))) + xv.z;
        res.w = g * (th[3] + h2f((ushort)(ow2.y >> 16))    * h2f((ushort)(aw2.y >> 16)))    + xv.w;
        *(float4*)(out + base) = res;
      }
    }
  }
}

extern "C" void kernel_launch(void* const* d_in, const int* in_sizes, int n_in,
                              void* d_out, int out_size, void* d_ws, size_t ws_size,
                              hipStream_t stream)
{
  const float* x     = (const float*)d_in[0];
  const float* Wq    = (const float*)d_in[1];
  const float* bq    = (const float*)d_in[2];
  const float* Wk    = (const float*)d_in[3];
  const float* bk    = (const float*)d_in[4];
  const float* Wv    = (const float*)d_in[5];
  const float* bv    = (const float*)d_in[6];
  const float* gamma = (const float*)d_in[7];
  float* out = (float*)d_out;

  char* w = (char*)d_ws;
  size_t np = (size_t)NB * HW * HW;
  ushort* W_frag = (ushort*)w; w += 6144 * 2;
  float*  bias_f = (float*)w;  w += 96 * 4 + 320;   // keep 16B alignment
  ushort* qT  = (ushort*)w;  w += np * 8 * 2;   // pixel-major 8ch transposed
  ushort* kT  = (ushort*)w;  w += np * 8 * 2;
  ushort* v   = (ushort*)w;  w += np * CC * 2;
  ushort* vT  = (ushort*)w;  w += np * CC * 2;
  ushort* oW  = (ushort*)w;  w += np * CC * 2;
  ushort* oHT = (ushort*)w;  w += np * CC * 2;
  float* mW = (float*)w;  w += np * 4;
  float* sW = (float*)w;  w += np * 4;
  ushort* aWn = (ushort*)w; w += np * 2;
  if ((size_t)(w - (char*)d_ws) > ws_size) return;

  k_prep<<<24, 256, 0, stream>>>(Wq, bq, Wk, bk, Wv, bv, W_frag, bias_f);
  k_projW<<<NB * HW, 256, 0, stream>>>(x, W_frag, bias_f, qT, kT, v, oW, mW, sW);
  k_transpose_v<<<NB * CC, 256, 0, stream>>>(v, vT);
  k_attnH<<<NB * HW, 256, 0, stream>>>(qT, kT, vT, mW, sW, oHT, aWn);
  k_merge<<<NB * 32 * 4, 256, 0, stream>>>(oHT, oW, aWn, x, gamma, out);
}